// Round 15
// baseline (88.456 us; speedup 1.0000x reference)
//
#include <hip/hip_runtime.h>
#include <hip/hip_bf16.h>

#define FD 256      // feature dim
#define NTOT 768    // Q|K|V channels
#define MT 16       // tokens per gemm block
#define ASTR 264    // bf16 row stride for A staging (256+8: 2-way banks = free)
#define NM 15       // Taylor moments

typedef __attribute__((ext_vector_type(8))) short bf16x8;
typedef __attribute__((ext_vector_type(4))) float f32x4;

__device__ __forceinline__ float fast_rcp(float x) {
#if __has_builtin(__builtin_amdgcn_rcpf)
    return __builtin_amdgcn_rcpf(x);
#else
    return 1.0f / x;
#endif
}

__device__ __forceinline__ unsigned bits(float a) {
    union { float f; unsigned u; } c; c.f = a; return c.u;
}
__device__ __forceinline__ float hi_f(float a) {       // bf16-truncated value
    union { unsigned u; float f; } c; c.u = bits(a) & 0xFFFF0000u; return c.f;
}
__device__ __forceinline__ unsigned pack_hi2(float a, float b) {
    return (bits(a) >> 16) | (bits(b) & 0xFFFF0000u);  // two bf16 from tops
}

// ---------------------------------------------------------------------------
// Kernel 0: one-pass hi/lo bf16 split of x and W (hoists ALL repack VALU out
// of the GEMM K-loop; also halves K-loop W bytes). 2.75 MB -> 2.75 MB.
// Thread = one float4. x region first (nx4 float4), then W (768*64 float4,
// rows ordered Q|K|V).
// ---------------------------------------------------------------------------
__global__ __launch_bounds__(256) void prep_split(
    const float* __restrict__ x,
    const float* __restrict__ Wq, const float* __restrict__ Wk,
    const float* __restrict__ Wv,
    short* __restrict__ xh, short* __restrict__ xl,
    short* __restrict__ wh, short* __restrict__ wl, int nx4)
{
    const int i = blockIdx.x * 256 + threadIdx.x;
    float4 v;
    short *dh, *dl;
    size_t doff;
    if (i < nx4) {
        v = *(const float4*)(x + (size_t)i * 4);
        dh = xh; dl = xl; doff = (size_t)i * 4;
    } else {
        const int j = i - nx4;
        const int ch = j >> 6, k4 = j & 63;
        const float* __restrict__ Wp = (ch < 256) ? Wq : (ch < 512) ? Wk : Wv;
        v = *(const float4*)(Wp + (size_t)(ch & 255) * FD + k4 * 4);
        dh = wh; dl = wl; doff = (size_t)j * 4;
    }
    uint2 ph, pl;
    ph.x = pack_hi2(v.x, v.y); ph.y = pack_hi2(v.z, v.w);
    pl.x = pack_hi2(v.x - hi_f(v.x), v.y - hi_f(v.y));
    pl.y = pack_hi2(v.z - hi_f(v.z), v.w - hi_f(v.w));
    *(uint2*)(dh + doff) = ph;
    *(uint2*)(dl + doff) = pl;
}

// ---------------------------------------------------------------------------
// Kernel 1: QKV = x @ W^T + b via split-bf16 MFMA (C ~= AhBh+AhBl+AlBh;
// dropped AlBl ~2^-16 rel). Block = 16 tok x 64 ch, 4 waves, wave = one
// 16x16 n-tile; grid 128 x 12 = 6 blocks/CU (R14 TLP). K-loop is now PURE:
// 2 ds_read_b128 + 2 global 16B bf16 loads + 3 MFMA per step — all hi/lo
// splitting was hoisted into prep_split. Frag layouts (m89-verified):
// A[m=lane&15][k=quad*8+j]; B[n=lane&15][k]; D: tok=quad*4+reg, ch=lane&15.
// ---------------------------------------------------------------------------
__global__ __launch_bounds__(256, 6) void qkv_gemm(
    const short* __restrict__ xh, const short* __restrict__ xl,
    const short* __restrict__ wh, const short* __restrict__ wl,
    const float* __restrict__ bq, const float* __restrict__ bk,
    const float* __restrict__ bv, float* __restrict__ qkv)
{
    __shared__ __align__(16) short Ah[MT * ASTR], Al[MT * ASTR];   // 16.9 KB

    const int tid  = threadIdx.x;
    const int lane = tid & 63;
    const int wid  = tid >> 6;
    const int ln   = lane & 15;
    const int quad = lane >> 4;
    const int t0   = blockIdx.x * MT;
    const int chb  = blockIdx.y * 64;       // 64-ch block: single matrix

    // ---- stage pre-split x tile (16 tok x 256 k, hi+lo) : 4 uint4/thread ----
    #pragma unroll
    for (int u = 0; u < 4; ++u) {
        const int linear = u * 256 + tid;   // 0..1023
        const int half = linear >> 9;       // 0 -> Ah, 1 -> Al
        const int idx  = linear & 511;
        const int r = idx >> 5, c = (idx & 31) * 8;
        const short* __restrict__ src =
            (half ? xl : xh) + (size_t)(t0 + r) * FD + c;
        short* dst = (half ? Al : Ah) + r * ASTR + c;
        *(uint4*)dst = *(const uint4*)src;
    }
    __syncthreads();

    // ---- K-loop: barrier-free, zero repack ----
    const int chrow = chb + wid * 16 + ln;
    const short* __restrict__ whp = wh + (size_t)chrow * FD;
    const short* __restrict__ wlp = wl + (size_t)chrow * FD;

    f32x4 acc = (f32x4){0.f, 0.f, 0.f, 0.f};
    #pragma unroll
    for (int s = 0; s < 8; ++s) {
        const bf16x8 ah = *(const bf16x8*)&Ah[ln * ASTR + s * 32 + quad * 8];
        const bf16x8 al = *(const bf16x8*)&Al[ln * ASTR + s * 32 + quad * 8];
        const bf16x8 bh = *(const bf16x8*)(whp + s * 32 + quad * 8);
        const bf16x8 bl = *(const bf16x8*)(wlp + s * 32 + quad * 8);
        acc = __builtin_amdgcn_mfma_f32_16x16x32_bf16(ah, bh, acc, 0, 0, 0);
        acc = __builtin_amdgcn_mfma_f32_16x16x32_bf16(ah, bl, acc, 0, 0, 0);
        acc = __builtin_amdgcn_mfma_f32_16x16x32_bf16(al, bh, acc, 0, 0, 0);
    }

    // ---- epilogue: bias + store ----
    const float* __restrict__ bp = (chb < 256) ? bq : (chb < 512) ? bk : bv;
    const float bias = bp[(chrow & 255)];
    #pragma unroll
    for (int reg = 0; reg < 4; ++reg) {
        const int tok = quad * 4 + reg;
        qkv[(size_t)(t0 + tok) * NTOT + chrow] = acc[reg] + bias;
    }
}

// ---------------------------------------------------------------------------
// Kernel 2: Taylor-moment softmax-attention (R8, known-good).
// f(c)=sum_n c^n M_n/n!, M_n=sum_j k_j^n v_j; degree-14 remainder < 1e-6.
// ---------------------------------------------------------------------------
__global__ __launch_bounds__(256) void attn_eval(
    const float* __restrict__ qkv, float* __restrict__ out)
{
    const int t = blockIdx.x * 4 + (threadIdx.x >> 6);
    const int l = threadIdx.x & 63;
    const float* __restrict__ base = qkv + (size_t)t * NTOT;

    const float4 k4 = *(const float4*)(base + FD + 4 * l);
    const float4 v4 = *(const float4*)(base + 2 * FD + 4 * l);
    const float ke[4] = {k4.x, k4.y, k4.z, k4.w};
    const float ve[4] = {v4.x, v4.y, v4.z, v4.w};

    float G[NM], Mo[NM];
    #pragma unroll
    for (int n = 0; n < NM; ++n) { G[n] = 0.f; Mo[n] = 0.f; }
    #pragma unroll
    for (int e = 0; e < 4; ++e) {
        float kp = 1.f;
        #pragma unroll
        for (int n = 0; n < NM; ++n) {
            G[n] += kp;
            Mo[n] = fmaf(kp, ve[e], Mo[n]);
            kp *= ke[e];
        }
    }
    #pragma unroll
    for (int n = 0; n < NM; ++n) {
        #pragma unroll
        for (int off = 1; off < 64; off <<= 1) {
            G[n]  += __shfl_xor(G[n],  off);
            Mo[n] += __shfl_xor(Mo[n], off);
        }
    }

    constexpr float inv_fact[NM] = {
        1.f, 1.f, 0.5f, 1.f/6.f, 1.f/24.f, 1.f/120.f, 1.f/720.f,
        1.f/5040.f, 1.f/40320.f, 1.f/362880.f, 1.f/3628800.f,
        1.f/39916800.f, 1.f/479001600.f, 1.f/6227020800.f,
        1.f/87178291200.f};
    float am[NM], ag[NM];
    #pragma unroll
    for (int n = 0; n < NM; ++n) {
        am[n] = Mo[n] * inv_fact[n];
        ag[n] = G[n]  * inv_fact[n];
    }

    const float4 q4v = *(const float4*)(base + 4 * l);
    const float qe[4] = {q4v.x, q4v.y, q4v.z, q4v.w};
    float re[4];
    #pragma unroll
    for (int e = 0; e < 4; ++e) {
        const float cc = qe[e] * 0.0625f;   // c = Q_i / sqrt(256)
        float Pm = am[NM - 1], Pg = ag[NM - 1];
        #pragma unroll
        for (int n = NM - 2; n >= 0; --n) {
            Pm = fmaf(Pm, cc, am[n]);
            Pg = fmaf(Pg, cc, ag[n]);
        }
        re[e] = Pm * fast_rcp(Pg);
    }
    float4 res; res.x = re[0]; res.y = re[1]; res.z = re[2]; res.w = re[3];
    *(float4*)(out + (size_t)t * FD + 4 * l) = res;
}

extern "C" void kernel_launch(void* const* d_in, const int* in_sizes, int n_in,
                              void* d_out, int out_size, void* d_ws, size_t ws_size,
                              hipStream_t stream) {
    const float* x  = (const float*)d_in[0];
    const float* Wq = (const float*)d_in[1];
    const float* bq = (const float*)d_in[2];
    const float* Wk = (const float*)d_in[3];
    const float* bk = (const float*)d_in[4];
    const float* Wv = (const float*)d_in[5];
    const float* bv = (const float*)d_in[6];
    float* out = (float*)d_out;

    const int M = in_sizes[0] / FD;   // 2048 tokens

    // workspace layout (byte offsets, all 16B-aligned)
    char* ws = (char*)d_ws;
    float* qkv = (float*)ws;                               // M*768 f32
    size_t off = (size_t)M * NTOT * 4;
    short* xh = (short*)(ws + off);  off += (size_t)M * FD * 2;
    short* xl = (short*)(ws + off);  off += (size_t)M * FD * 2;
    short* wh = (short*)(ws + off);  off += (size_t)NTOT * FD * 2;
    short* wl = (short*)(ws + off);

    const int nx4 = M * (FD / 4);                          // x float4 count
    const int ntot4 = nx4 + NTOT * (FD / 4);
    prep_split<<<ntot4 / 256, 256, 0, stream>>>(x, Wq, Wk, Wv,
                                                xh, xl, wh, wl, nx4);
    dim3 g1(M / MT, NTOT / 64);       // 128 x 12 = 1536 blocks
    qkv_gemm<<<g1, 256, 0, stream>>>(xh, xl, wh, wl, bq, bk, bv, qkv);
    attn_eval<<<M / 4, 256, 0, stream>>>(qkv, out);
}